// Round 8
// baseline (525.455 us; speedup 1.0000x reference)
//
#include <hip/hip_runtime.h>
#include <math.h>

#define B_SZ 8192
#define D_DIM 512
#define C_DIM 1000
#define C_PAD 1024
#define K_EXP 8
#define TEMP_INV 5.0f
#define EPS_N 1e-8f

typedef __attribute__((ext_vector_type(8))) short frag_ab;
typedef __attribute__((ext_vector_type(4))) float frag_cd;

__device__ __forceinline__ short f2bf(float f) {
    unsigned u = __builtin_bit_cast(unsigned, f);
    unsigned r = (u + 0x7fffu + ((u >> 16) & 1u)) >> 16;
    return (short)r;
}
__device__ __forceinline__ float bf2f(short s) {
    unsigned u = ((unsigned)(unsigned short)s) << 16;
    return __builtin_bit_cast(float, u);
}
// 2-plane split: v ~= s0 + s1, |residual| ~ 2^-18 |v|
__device__ __forceinline__ void split2(float v, short& s0, short& s1) {
    s0 = f2bf(v);
    s1 = f2bf(v - bf2f(s0));
}

// async global->LDS, 16B per lane (LDS dest wave-contiguous: base + lane*16)
__device__ __forceinline__ void gl_lds16(const short* g, short* l) {
    __builtin_amdgcn_global_load_lds(
        (const __attribute__((address_space(1))) unsigned int*)(const void*)g,
        (__attribute__((address_space(3))) unsigned int*)(void*)l,
        16, 0, 0);
}

// ---------------- one-time prep: transpose + 2-way bf16 split ----------------
__global__ __launch_bounds__(256) void prep_z(const float* __restrict__ z,
                                              short* __restrict__ p0, short* __restrict__ p1) {
    int idx = blockIdx.x * 256 + threadIdx.x;
    float v = z[idx];
    short a, b; split2(v, a, b);
    p0[idx] = a; p1[idx] = b;
}

// W1 [K][d][e] -> planes [K][e][d], LDS 32x32 tile transpose
__global__ __launch_bounds__(256) void prep_w1t(const float* __restrict__ W1,
                                                short* __restrict__ p0, short* __restrict__ p1) {
    __shared__ float t[32][33];
    const int k = blockIdx.z;
    const int d0 = blockIdx.x * 32;
    const int e0 = blockIdx.y * 32;
    const int tx = threadIdx.x & 31, ty = threadIdx.x >> 5;
    const float* src = W1 + ((size_t)k << 18);
#pragma unroll
    for (int r = 0; r < 4; r++) {
        int d = d0 + ty + 8 * r;
        t[ty + 8 * r][tx] = src[(size_t)d * 512 + e0 + tx];
    }
    __syncthreads();
#pragma unroll
    for (int r = 0; r < 4; r++) {
        int e = e0 + ty + 8 * r;
        int d = d0 + tx;
        float v = t[tx][ty + 8 * r];
        short a, b; split2(v, a, b);
        size_t o = ((size_t)k << 18) + (size_t)e * 512 + d;
        p0[o] = a; p1[o] = b;
    }
}

// W2 [K][e][c] -> planes [K][c_pad][e] (zero rows c>=1000), 32x32 tile transpose
__global__ __launch_bounds__(256) void prep_w2t(const float* __restrict__ W2,
                                                short* __restrict__ p0, short* __restrict__ p1) {
    __shared__ float t[32][33];
    const int k = blockIdx.z;
    const int e0 = blockIdx.x * 32;
    const int c0 = blockIdx.y * 32;
    const int tx = threadIdx.x & 31, ty = threadIdx.x >> 5;
    const float* src = W2 + (size_t)k * (D_DIM * C_DIM);
#pragma unroll
    for (int r = 0; r < 4; r++) {
        int e = e0 + ty + 8 * r;
        int c = c0 + tx;
        t[ty + 8 * r][tx] = (c < C_DIM) ? src[(size_t)e * C_DIM + c] : 0.f;
    }
    __syncthreads();
#pragma unroll
    for (int r = 0; r < 4; r++) {
        int c = c0 + ty + 8 * r;
        int e = e0 + tx;
        float v = t[tx][ty + 8 * r];
        short a, b; split2(v, a, b);
        size_t o = (size_t)k * (C_PAD * D_DIM) + (size_t)c * 512 + e;
        p0[o] = a; p1[o] = b;
    }
}

// ---------------- split-bf16 MFMA GEMM: 256x256 block (512 thr), 128x64 wave tile ----------
// Single-buffer 64 KB LDS, BK=32, 3 MFMA products. 1 block/CU, 8 waves.
// Arithmetic intensity: 64 KB staged per 931 MFMA-cyc per CU-iter -> L2 cap ~81% util.
// Bank-swizzle: slot sc of row r holds k-chunk sc ^ ((r>>1)&3) (verified 0-conflict).
__global__ __launch_bounds__(512, 2) void gemm_split(
    const short* __restrict__ A0, const short* __restrict__ A1, long long aBatch,
    const short* __restrict__ B0, const short* __restrict__ B1, long long bBatch,
    const float* __restrict__ bias, int biasBatch,
    float* __restrict__ Cf, long long cBatch, int ldc, int Nout,
    short* __restrict__ H0, short* __restrict__ H1, long long hBatch,
    int mt, int nt, int mode)
{
    const int lin = blockIdx.x;
    const int k = lin & 7;                  // expert ↔ XCD affinity
    const int rem = lin >> 3;
    const int gm = (mt >= 2) ? 2 : 1;       // 512-row L2 m-window
    const int win = rem / (gm * nt);
    const int local = rem % (gm * nt);
    const int m0 = (win * gm + local / nt) * 256;
    const int n0 = (local % nt) * 256;

    const int tid = threadIdx.x;
    const int lane = tid & 63;
    const int wv = tid >> 6;                // 0..7
    const int wm = (wv & 1) * 128;          // wave tile: 128 rows x 64 cols
    const int wn = (wv >> 1) * 64;          // 4 col positions x 64

    __shared__ short lds[32768];            // A: 2 planes x 8192, B: 2 planes x 8192 (64 KB)

    const short* gA0 = A0 + (size_t)k * aBatch + (size_t)m0 * 512;
    const short* gA1 = A1 + (size_t)k * aBatch + (size_t)m0 * 512;
    const short* gB0 = B0 + (size_t)k * bBatch + (size_t)n0 * 512;
    const short* gB1 = B1 + (size_t)k * bBatch + (size_t)n0 * 512;
    short* ldsA = lds;
    short* ldsB = lds + 16384;

    frag_cd acc[8][4];
#pragma unroll
    for (int i = 0; i < 8; i++)
#pragma unroll
        for (int j = 0; j < 4; j++)
            acc[i][j] = (frag_cd){0.f, 0.f, 0.f, 0.f};

    const int srow = tid >> 2;              // 0..127
    const int sc   = tid & 3;               // LDS slot

    for (int k0 = 0; k0 < 512; k0 += 32) {
        const short* ga[2] = {gA0, gA1};
        const short* gb[2] = {gB0, gB1};
#pragma unroll
        for (int p = 0; p < 2; p++) {
#pragma unroll
            for (int hh = 0; hh < 2; hh++) {           // A: 256 rows
                int row = hh * 128 + srow;
                int gq = sc ^ ((row >> 1) & 3);
                gl_lds16(ga[p] + (size_t)row * 512 + k0 + gq * 8,
                         ldsA + p * 8192 + row * 32 + sc * 8);
            }
#pragma unroll
            for (int hh = 0; hh < 2; hh++) {           // B: 256 rows
                int row = hh * 128 + srow;
                int gq = sc ^ ((row >> 1) & 3);
                gl_lds16(gb[p] + (size_t)row * 512 + k0 + gq * 8,
                         ldsB + p * 8192 + row * 32 + sc * 8);
            }
        }
        __syncthreads();

        const int q = lane >> 4;
        const int rb = lane & 15;

        frag_ab bfr[2][4];
#pragma unroll
        for (int p = 0; p < 2; p++)
#pragma unroll
            for (int j = 0; j < 4; j++) {
                int R = wn + j * 16 + rb;
                int slot = q ^ ((R >> 1) & 3);
                bfr[p][j] = *(const frag_ab*)(ldsB + p * 8192 + R * 32 + slot * 8);
            }

#pragma unroll
        for (int i = 0; i < 8; i++) {
            int R = wm + i * 16 + rb;
            int slot = q ^ ((R >> 1) & 3);
            frag_ab a0 = *(const frag_ab*)(ldsA + R * 32 + slot * 8);
            frag_ab a1 = *(const frag_ab*)(ldsA + 8192 + R * 32 + slot * 8);
#pragma unroll
            for (int j = 0; j < 4; j++) {
                frag_cd c = acc[i][j];
                c = __builtin_amdgcn_mfma_f32_16x16x32_bf16(a0, bfr[0][j], c, 0, 0, 0);
                c = __builtin_amdgcn_mfma_f32_16x16x32_bf16(a0, bfr[1][j], c, 0, 0, 0);
                c = __builtin_amdgcn_mfma_f32_16x16x32_bf16(a1, bfr[0][j], c, 0, 0, 0);
                acc[i][j] = c;
            }
        }
        __syncthreads();
    }

    // epilogue: C/D layout col=lane&15, row=(lane>>4)*4+reg
    const int r0 = (lane >> 4) * 4;
    const int cc = lane & 15;
    if (mode == 0) {
        float* C = Cf + (size_t)k * cBatch;
        const float* bb = bias + (size_t)k * biasBatch;
#pragma unroll
        for (int i = 0; i < 8; i++) {
            int rowb = m0 + wm + i * 16 + r0;
#pragma unroll
            for (int j = 0; j < 4; j++) {
                int col = n0 + wn + j * 16 + cc;
                if (col < Nout) {
                    float b = bb[col];
#pragma unroll
                    for (int r = 0; r < 4; r++)
                        C[(size_t)(rowb + r) * ldc + col] = acc[i][j][r] + b;
                }
            }
        }
    } else {
        short* h0 = H0 + (size_t)k * hBatch;
        short* h1 = H1 + (size_t)k * hBatch;
        const float* bb = bias + (size_t)k * biasBatch;
#pragma unroll
        for (int i = 0; i < 8; i++) {
            int rowb = m0 + wm + i * 16 + r0;
#pragma unroll
            for (int j = 0; j < 4; j++) {
                int col = n0 + wn + j * 16 + cc;
                float b = bb[col];
#pragma unroll
                for (int r = 0; r < 4; r++) {
                    float v = fmaxf(acc[i][j][r] + b, 0.f);
                    short s0, s1; split2(v, s0, s1);
                    size_t o = (size_t)(rowb + r) * 512 + col;
                    h0[o] = s0; h1[o] = s1;
                }
            }
        }
    }
}

// ---------------- gate + combine: one wave per sample, wave-synchronous ----------------
__global__ __launch_bounds__(256) void gate_combine(
    const float* __restrict__ L,
    const int* __restrict__ n_exp,
    float* __restrict__ out_logits,   // [Bc][C] (offset)
    float* __restrict__ out_gates,    // [Bc][K] (offset)
    int Bc)
{
    const int wv = threadIdx.x >> 6;
    const int lane = threadIdx.x & 63;
    const int b = blockIdx.x * 4 + wv;
    const size_t kcs = (size_t)Bc * C_DIM;
    const float* Lb = L + (size_t)b * C_DIM;

    __shared__ float Sm[4][64];
    __shared__ float Zm[4][8];

    float mx[K_EXP], Zs[K_EXP], dd[36];
#pragma unroll
    for (int k = 0; k < K_EXP; k++) { mx[k] = -INFINITY; Zs[k] = 0.f; }
#pragma unroll
    for (int p = 0; p < 36; p++) dd[p] = 0.f;

    for (int c = lane; c < C_DIM; c += 64) {
        float e[K_EXP];
#pragma unroll
        for (int k = 0; k < K_EXP; k++) {
            float l = Lb[(size_t)k * kcs + c];
            mx[k] = fmaxf(mx[k], l);
            e[k] = __expf(l);
            Zs[k] += e[k];
        }
        int idx = 0;
#pragma unroll
        for (int i = 0; i < K_EXP; i++)
#pragma unroll
            for (int j = i; j < K_EXP; j++) {
                dd[idx] = fmaf(e[i], e[j], dd[idx]);
                idx++;
            }
    }

#pragma unroll
    for (int off = 32; off > 0; off >>= 1) {
#pragma unroll
        for (int k = 0; k < K_EXP; k++) {
            mx[k] = fmaxf(mx[k], __shfl_xor(mx[k], off, 64));
            Zs[k] += __shfl_xor(Zs[k], off, 64);
        }
#pragma unroll
        for (int p = 0; p < 36; p++)
            dd[p] += __shfl_xor(dd[p], off, 64);
    }

    if (lane == 0) {
        int idx = 0;
#pragma unroll
        for (int i = 0; i < K_EXP; i++)
#pragma unroll
            for (int j = i; j < K_EXP; j++) {
                Sm[wv][i * 8 + j] = dd[idx];
                Sm[wv][j * 8 + i] = dd[idx];
                idx++;
            }
#pragma unroll
        for (int k = 0; k < K_EXP; k++) Zm[wv][k] = Zs[k];
    }

    const int ti = lane >> 3, tj = lane & 7;
    const float Zi = Zm[wv][ti], Zj = Zm[wv][tj];
    const float dij = Sm[wv][ti * 8 + tj];
    const float dii = Sm[wv][ti * 8 + ti];
    const float djj = Sm[wv][tj * 8 + tj];
    const float ni = sqrtf(dii) / Zi + EPS_N;
    const float nj = sqrtf(djj) / Zj + EPS_N;
    const float cosij = (dij / (Zi * Zj)) / (ni * nj);

    float conf[K_EXP];
#pragma unroll
    for (int k = 0; k < K_EXP; k++) conf[k] = __expf(mx[k]) / Zs[k];

    int i0 = 0; float bcf = conf[0];
#pragma unroll
    for (int k = 1; k < K_EXP; k++)
        if (conf[k] > bcf) { bcf = conf[k]; i0 = k; }
    unsigned sel = 1u << i0;
    const int n = n_exp[b];

    for (int t = 1; t < K_EXP; t++) {
        float v = ((sel >> tj) & 1u) ? cosij : -INFINITY;
        v = fmaxf(v, __shfl_xor(v, 1, 64));
        v = fmaxf(v, __shfl_xor(v, 2, 64));
        v = fmaxf(v, __shfl_xor(v, 4, 64));
        float dist = ((sel >> ti) & 1u) ? -INFINITY : 1.0f - v;
        float bv = dist; int bi = ti;
#pragma unroll
        for (int off = 8; off < 64; off <<= 1) {
            float ov = __shfl_xor(bv, off, 64);
            int oi = __shfl_xor(bi, off, 64);
            if (ov > bv || (ov == bv && oi < bi)) { bv = ov; bi = oi; }
        }
        if (t < n) sel |= 1u << bi;
    }

    float cmax = -INFINITY;
#pragma unroll
    for (int k = 0; k < K_EXP; k++)
        if ((sel >> k) & 1u) cmax = fmaxf(cmax, conf[k]);
    float g[K_EXP], gsum = 0.f;
#pragma unroll
    for (int k = 0; k < K_EXP; k++) {
        g[k] = ((sel >> k) & 1u) ? __expf((conf[k] - cmax) * TEMP_INV) : 0.f;
        gsum += g[k];
    }
    const float ginv = 1.0f / gsum;
#pragma unroll
    for (int k = 0; k < K_EXP; k++) g[k] *= ginv;

    if (lane == 0) {
        float4* og = (float4*)(out_gates + (size_t)b * K_EXP);
        og[0] = make_float4(g[0], g[1], g[2], g[3]);
        og[1] = make_float4(g[4], g[5], g[6], g[7]);
    }

    for (int c = lane; c < C_DIM; c += 64) {
        float o = 0.f;
#pragma unroll
        for (int k = 0; k < K_EXP; k++)
            o = fmaf(g[k], Lb[(size_t)k * kcs + c], o);
        out_logits[(size_t)b * C_DIM + c] = o;
    }
}

// ---------------- launch ----------------
extern "C" void kernel_launch(void* const* d_in, const int* in_sizes, int n_in,
                              void* d_out, int out_size, void* d_ws, size_t ws_size,
                              hipStream_t stream) {
    const float* z     = (const float*)d_in[0];
    const int*   n_exp = (const int*)d_in[1];
    const float* W1    = (const float*)d_in[2];
    const float* b1    = (const float*)d_in[3];
    const float* W2    = (const float*)d_in[4];
    const float* b2    = (const float*)d_in[5];
    float* out_logits = (float*)d_out;
    float* out_gates  = (float*)d_out + (size_t)B_SZ * C_DIM;

    const size_t zP   = (size_t)B_SZ * D_DIM * 2;
    const size_t w1P  = (size_t)K_EXP * D_DIM * D_DIM * 2;
    const size_t w2P  = (size_t)K_EXP * C_PAD * D_DIM * 2;
    const size_t fixedBytes = 2 * (zP + w1P + w2P);   // ~42 MB

    int nch = 1;
    while (nch < 32 && fixedBytes + (size_t)(B_SZ / nch) * 48384 > ws_size) nch *= 2;
    const int Bc = B_SZ / nch;

    char* w = (char*)d_ws;
    short* zp[2];  zp[0]  = (short*)w; zp[1]  = (short*)(w + zP);  w += 2 * zP;
    short* w1t[2]; w1t[0] = (short*)w; w1t[1] = (short*)(w + w1P); w += 2 * w1P;
    short* w2t[2]; w2t[0] = (short*)w; w2t[1] = (short*)(w + w2P); w += 2 * w2P;
    const size_t hP = (size_t)K_EXP * Bc * D_DIM * 2;
    short* hp[2];  hp[0]  = (short*)w; hp[1]  = (short*)(w + hP);  w += 2 * hP;
    float* Lb = (float*)w;

    prep_z <<<dim3((B_SZ * D_DIM) / 256), 256, 0, stream>>>(z, zp[0], zp[1]);
    prep_w1t<<<dim3(16, 16, K_EXP), 256, 0, stream>>>(W1, w1t[0], w1t[1]);
    prep_w2t<<<dim3(16, 32, K_EXP), 256, 0, stream>>>(W2, w2t[0], w2t[1]);

    const int mt = Bc / 256;    // 256-row m-tiles

    for (int ch = 0; ch < nch; ch++) {
        const int off = ch * Bc;
        const long long zoff = (long long)off * D_DIM;

        // GEMM1: N=512 -> nt=2 (256-col tiles)
        gemm_split<<<dim3(8 * mt * 2), 512, 0, stream>>>(
            zp[0] + zoff, zp[1] + zoff, 0LL,
            w1t[0], w1t[1], (long long)D_DIM * D_DIM,
            b1, D_DIM,
            nullptr, 0LL, 0, D_DIM,
            hp[0], hp[1], (long long)Bc * D_DIM,
            mt, 2, 1);

        // GEMM2: N=1024 -> nt=4
        gemm_split<<<dim3(8 * mt * 4), 512, 0, stream>>>(
            hp[0], hp[1], (long long)Bc * D_DIM,
            w2t[0], w2t[1], (long long)C_PAD * D_DIM,
            b2, C_DIM,
            Lb, (long long)Bc * C_DIM, C_DIM, C_DIM,
            nullptr, nullptr, 0LL,
            mt, 4, 0);

        gate_combine<<<dim3(Bc / 4), 256, 0, stream>>>(
            Lb, n_exp + off,
            out_logits + (size_t)off * C_DIM,
            out_gates + (size_t)off * K_EXP,
            Bc);
    }
}